// Round 1
// baseline (5144.827 us; speedup 1.0000x reference)
//
#include <hip/hip_runtime.h>
#include <hip/hip_bf16.h>
#include <cstddef>

// Problem constants
#define BATCH 16
#define TSTEPS 128
#define MSLOTS 512
#define DIN 256
#define UNITS 256
#define ZDIM 1024   // 4*UNITS

__device__ __forceinline__ float tanhf_fast(float x) {
    // tanh(x) = 1 - 2/(exp(2x)+1); exp overflow -> inf -> 1; underflow -> 0 -> -1. Both correct.
    float e = __expf(2.0f * x);
    return 1.0f - 2.0f / (e + 1.0f);
}
__device__ __forceinline__ float sigmoidf_fast(float x) {
    return 1.0f / (1.0f + __expf(-x));
}

// ---------------------------------------------------------------------------
// Generic f32 GEMM with bias: C[M][N] = A[M][K] @ B[K][N] + bias[N]
// Requires M%64==0, N%64==0, K%16==0. 256 threads, 64x64 tile, 4x4 per thread.
// ---------------------------------------------------------------------------
__global__ __launch_bounds__(256) void gemm_bias_kernel(
    const float* __restrict__ A, const float* __restrict__ B,
    const float* __restrict__ bias, float* __restrict__ C,
    int M, int N, int K)
{
    __shared__ float As[16][64 + 4];  // stored transposed: As[k][m]
    __shared__ float Bs[16][64 + 4];
    const int tid = threadIdx.x;
    const int bm = blockIdx.x * 64;
    const int bn = blockIdx.y * 64;
    const int tx = tid & 15, ty = tid >> 4;
    const int ar = tid >> 2, ac = (tid & 3) * 4;    // A: 64 rows x 16 k
    const int br = tid >> 4, bc = (tid & 15) * 4;   // B: 16 k x 64 cols
    float acc[4][4] = {};

    for (int k0 = 0; k0 < K; k0 += 16) {
        float4 av = *(const float4*)(A + (size_t)(bm + ar) * K + k0 + ac);
        float4 bv = *(const float4*)(B + (size_t)(k0 + br) * N + bn + bc);
        As[ac + 0][ar] = av.x; As[ac + 1][ar] = av.y;
        As[ac + 2][ar] = av.z; As[ac + 3][ar] = av.w;
        *(float4*)(&Bs[br][bc]) = bv;   // (br*68+bc)%4==0 -> 16B aligned
        __syncthreads();
#pragma unroll
        for (int kk = 0; kk < 16; ++kk) {
            float a0 = As[kk][ty * 4 + 0], a1 = As[kk][ty * 4 + 1];
            float a2 = As[kk][ty * 4 + 2], a3 = As[kk][ty * 4 + 3];
            float b0 = Bs[kk][tx * 4 + 0], b1 = Bs[kk][tx * 4 + 1];
            float b2 = Bs[kk][tx * 4 + 2], b3 = Bs[kk][tx * 4 + 3];
            acc[0][0] += a0 * b0; acc[0][1] += a0 * b1; acc[0][2] += a0 * b2; acc[0][3] += a0 * b3;
            acc[1][0] += a1 * b0; acc[1][1] += a1 * b1; acc[1][2] += a1 * b2; acc[1][3] += a1 * b3;
            acc[2][0] += a2 * b0; acc[2][1] += a2 * b1; acc[2][2] += a2 * b2; acc[2][3] += a2 * b3;
            acc[3][0] += a3 * b0; acc[3][1] += a3 * b1; acc[3][2] += a3 * b2; acc[3][3] += a3 * b3;
        }
        __syncthreads();
    }
#pragma unroll
    for (int i = 0; i < 4; ++i) {
#pragma unroll
        for (int j = 0; j < 4; ++j) {
            int cn = bn + tx * 4 + j;
            C[(size_t)(bm + ty * 4 + i) * N + cn] = acc[i][j] + bias[cn];
        }
    }
}

// ---------------------------------------------------------------------------
// q = h_prev @ query_W + query_b      (grid: 16 blocks = batches, 256 thr)
// ---------------------------------------------------------------------------
__global__ __launch_bounds__(256) void k_q(
    const float* __restrict__ hprev, const float* __restrict__ Wq,
    const float* __restrict__ qb, float* __restrict__ q)
{
    const int b = blockIdx.x;
    const int tid = threadIdx.x;
    __shared__ float hs[UNITS];
    hs[tid] = hprev[b * UNITS + tid];
    __syncthreads();
    float acc = qb[tid];
#pragma unroll 8
    for (int k = 0; k < UNITS; ++k)
        acc += hs[k] * Wq[(size_t)k * UNITS + tid];
    q[b * UNITS + tid] = acc;
}

// ---------------------------------------------------------------------------
// scores[b][m] = sum_j tanh(keys[b][m][j] + q[b][j]) * aw[j] + attn_b
// grid: (8 chunks, 16 batches), 256 thr = 4 waves; wave handles 16 rows
// ---------------------------------------------------------------------------
__global__ __launch_bounds__(256) void k_scores(
    const float* __restrict__ keys, const float* __restrict__ q,
    const float* __restrict__ aw, const float* __restrict__ attn_b,
    float* __restrict__ scores)
{
    const int chunk = blockIdx.x;   // 0..7
    const int b = blockIdx.y;       // 0..15
    const int tid = threadIdx.x;
    const int wave = tid >> 6, lane = tid & 63;
    __shared__ float qs[UNITS];
    __shared__ float aws[UNITS];
    qs[tid] = q[b * UNITS + tid];
    aws[tid] = aw[tid];
    __syncthreads();

    const float ab0 = attn_b[0];
    float q0 = qs[lane * 4 + 0], q1 = qs[lane * 4 + 1];
    float q2 = qs[lane * 4 + 2], q3 = qs[lane * 4 + 3];
    float a0 = aws[lane * 4 + 0], a1 = aws[lane * 4 + 1];
    float a2 = aws[lane * 4 + 2], a3 = aws[lane * 4 + 3];

    for (int r = 0; r < 16; ++r) {
        int m = chunk * 64 + wave * 16 + r;
        const float4* kp = (const float4*)(keys + ((size_t)b * MSLOTS + m) * UNITS);
        float4 kv = kp[lane];
        float s = tanhf_fast(kv.x + q0) * a0
                + tanhf_fast(kv.y + q1) * a1
                + tanhf_fast(kv.z + q2) * a2
                + tanhf_fast(kv.w + q3) * a3;
#pragma unroll
        for (int off = 32; off > 0; off >>= 1)
            s += __shfl_down(s, off);
        if (lane == 0)
            scores[b * MSLOTS + m] = s + ab0;
    }
}

// ---------------------------------------------------------------------------
// softmax (redundant per block) + partial context:
// ctxp[b][mc][k] = (1/denom) * sum_{m in chunk mc} exp(s_m - max) * attended[b][m][k]
// grid: (4 m-chunks, 16 batches), 256 thr (thread = k)
// ---------------------------------------------------------------------------
__global__ __launch_bounds__(256) void k_ctx(
    const float* __restrict__ scores, const float* __restrict__ attended,
    float* __restrict__ ctxp)
{
    const int mc = blockIdx.x;   // 0..3
    const int b = blockIdx.y;    // 0..15
    const int tid = threadIdx.x;
    __shared__ float ps[MSLOTS];
    __shared__ float red[256];

    float s0 = scores[b * MSLOTS + tid];
    float s1 = scores[b * MSLOTS + 256 + tid];
    red[tid] = fmaxf(s0, s1);
    __syncthreads();
#pragma unroll
    for (int off = 128; off > 0; off >>= 1) {
        if (tid < off) red[tid] = fmaxf(red[tid], red[tid + off]);
        __syncthreads();
    }
    float mx = red[0];
    __syncthreads();
    float p0 = __expf(s0 - mx);
    float p1 = __expf(s1 - mx);
    ps[tid] = p0;
    ps[256 + tid] = p1;
    red[tid] = p0 + p1;
    __syncthreads();
#pragma unroll
    for (int off = 128; off > 0; off >>= 1) {
        if (tid < off) red[tid] += red[tid + off];
        __syncthreads();
    }
    float inv = 1.0f / red[0];

    float acc = 0.0f;
    const float* Ab = attended + ((size_t)b * MSLOTS + mc * 128) * DIN;
#pragma unroll 4
    for (int r = 0; r < 128; ++r)
        acc += ps[mc * 128 + r] * Ab[(size_t)r * DIN + tid];
    ctxp[((b << 2) + mc) * DIN + tid] = acc * inv;
}

// ---------------------------------------------------------------------------
// z = pre[b][t] + [ctx; h] @ [W2; U]; gates; c,h update; write seq (+hT,cT at t=127)
// grid: (16 j-slices, 16 batches), 256 thr.
// thread: j_l = tid&15, g = (tid>>4)&3, kq = tid>>6 (k-quarter of 512)
// ---------------------------------------------------------------------------
__global__ __launch_bounds__(256) void k_z(
    const float* __restrict__ ctxp, const float* __restrict__ hprev,
    float* __restrict__ c, const float* __restrict__ pre,
    const float* __restrict__ lstm_W, const float* __restrict__ lstm_U,
    float* __restrict__ hcur, float* __restrict__ seq,
    float* __restrict__ hT, float* __restrict__ cT, int t)
{
    const int js = blockIdx.x;   // 0..15
    const int b = blockIdx.y;    // 0..15
    const int tid = threadIdx.x;
    __shared__ float xin[512];
    __shared__ float zp[4][64];
    __shared__ float zg[64];

    // build xin = [ctx(256); h(256)]
    {
        float v = 0.0f;
#pragma unroll
        for (int mc = 0; mc < 4; ++mc)
            v += ctxp[((b << 2) + mc) * DIN + tid];
        xin[tid] = v;
        xin[256 + tid] = hprev[b * UNITS + tid];
    }
    __syncthreads();

    const int j_l = tid & 15;
    const int g = (tid >> 4) & 3;
    const int kq = tid >> 6;           // wave-uniform
    const int col = g * 256 + js * 16 + j_l;

    const float* Wp;
    if (kq < 2) Wp = lstm_W + ((size_t)(256 + kq * 128)) * ZDIM + col;
    else        Wp = lstm_U + ((size_t)((kq - 2) * 128)) * ZDIM + col;
    const float* xp = xin + kq * 128;

    float acc = 0.0f;
#pragma unroll 8
    for (int kk = 0; kk < 128; ++kk)
        acc += xp[kk] * Wp[(size_t)kk * ZDIM];
    zp[kq][g * 16 + j_l] = acc;
    __syncthreads();

    if (tid < 64) {
        int gg = tid >> 4, jl = tid & 15;
        int colz = gg * 256 + js * 16 + jl;
        float z = pre[((size_t)(b * TSTEPS + t)) * ZDIM + colz]
                + zp[0][tid] + zp[1][tid] + zp[2][tid] + zp[3][tid];
        zg[tid] = z;
    }
    __syncthreads();

    if (tid < 16) {
        int j = js * 16 + tid;
        float zi = zg[tid];
        float zf = zg[16 + tid];
        float zgg = zg[32 + tid];
        float zo = zg[48 + tid];
        float ig = sigmoidf_fast(zi);
        float fg = sigmoidf_fast(zf);
        float gg = tanhf_fast(zgg);
        float og = sigmoidf_fast(zo);
        float c_old = c[b * UNITS + j];
        float c_new = fg * c_old + ig * gg;
        float h_new = og * tanhf_fast(c_new);
        c[b * UNITS + j] = c_new;
        hcur[b * UNITS + j] = h_new;
        seq[((size_t)(b * TSTEPS + t)) * UNITS + j] = h_new;
        if (t == TSTEPS - 1) {
            hT[b * UNITS + j] = h_new;
            cT[b * UNITS + j] = c_new;
        }
    }
}

// ---------------------------------------------------------------------------
extern "C" void kernel_launch(void* const* d_in, const int* in_sizes, int n_in,
                              void* d_out, int out_size, void* d_ws, size_t ws_size,
                              hipStream_t stream)
{
    (void)in_sizes; (void)n_in; (void)out_size; (void)ws_size;
    const float* inputs   = (const float*)d_in[0];   // (16,128,256)
    const float* attended = (const float*)d_in[1];   // (16,512,256)
    const float* key_W    = (const float*)d_in[2];   // (256,256)
    const float* key_b    = (const float*)d_in[3];   // (256)
    const float* query_W  = (const float*)d_in[4];   // (256,256)
    const float* query_b  = (const float*)d_in[5];   // (256)
    const float* attn_W   = (const float*)d_in[6];   // (256,1) -> flat 256
    const float* attn_b   = (const float*)d_in[7];   // (1)
    const float* lstm_W   = (const float*)d_in[8];   // (512,1024)
    const float* lstm_U   = (const float*)d_in[9];   // (256,1024)
    const float* lstm_b   = (const float*)d_in[10];  // (1024)

    float* out = (float*)d_out;
    float* seq = out;                                  // 16*128*256
    float* hT  = out + (size_t)BATCH * TSTEPS * UNITS; // 16*256
    float* cT  = hT + BATCH * UNITS;                   // 16*256

    float* ws = (float*)d_ws;
    float* keys   = ws;                      // 16*512*256 = 2097152
    float* pre    = keys + 2097152;          // 16*128*1024 = 2097152
    float* q      = pre + 2097152;           // 16*256 = 4096
    float* scores = q + 4096;                // 16*512 = 8192
    float* ctxp   = scores + 8192;           // 16*4*256 = 16384
    float* hbuf   = ctxp + 16384;            // 2*16*256 = 8192 (double-buffered h)
    float* cbuf   = hbuf + 8192;             // 16*256 = 4096

    hipMemsetAsync(hbuf, 0, 8192 * sizeof(float), stream);
    hipMemsetAsync(cbuf, 0, 4096 * sizeof(float), stream);

    // keys = attended @ key_W + key_b : (8192 x 256) <- (8192 x 256)(256 x 256)
    gemm_bias_kernel<<<dim3(8192 / 64, 256 / 64), 256, 0, stream>>>(
        attended, key_W, key_b, keys, 8192, 256, 256);
    // pre = inputs @ lstm_W[:256] + lstm_b : (2048 x 1024)
    gemm_bias_kernel<<<dim3(2048 / 64, 1024 / 64), 256, 0, stream>>>(
        inputs, lstm_W, lstm_b, pre, 2048, 1024, 256);

    for (int t = 0; t < TSTEPS; ++t) {
        const float* hprev = hbuf + (size_t)((t + 1) & 1) * (BATCH * UNITS);
        float* hcur        = hbuf + (size_t)(t & 1) * (BATCH * UNITS);

        k_q<<<dim3(BATCH), 256, 0, stream>>>(hprev, query_W, query_b, q);
        k_scores<<<dim3(8, BATCH), 256, 0, stream>>>(keys, q, attn_W, attn_b, scores);
        k_ctx<<<dim3(4, BATCH), 256, 0, stream>>>(scores, attended, ctxp);
        k_z<<<dim3(16, BATCH), 256, 0, stream>>>(ctxp, hprev, cbuf, pre,
                                                 lstm_W, lstm_U, hcur, seq, hT, cT, t);
    }
}

// Round 2
// 4366.291 us; speedup vs baseline: 1.1783x; 1.1783x over previous
//
#include <hip/hip_runtime.h>
#include <hip/hip_bf16.h>
#include <cstddef>

#define BATCH 16
#define TSTEPS 128
#define MSLOTS 512
#define DIN 256
#define UNITS 256
#define ZDIM 1024
#define G 8          // blocks per batch
#define NBLK (BATCH*G)
#define NTHR 512

__device__ __forceinline__ float tanhf_fast(float x) {
    float e = __expf(2.0f * x);
    return 1.0f - 2.0f / (e + 1.0f);
}
__device__ __forceinline__ float sigmoidf_fast(float x) {
    return 1.0f / (1.0f + __expf(-x));
}
__device__ __forceinline__ void st_agent(float* p, float v) {
    __hip_atomic_store(p, v, __ATOMIC_RELAXED, __HIP_MEMORY_SCOPE_AGENT);
}
__device__ __forceinline__ float ld_agent(const float* p) {
    return __hip_atomic_load(p, __ATOMIC_RELAXED, __HIP_MEMORY_SCOPE_AGENT);
}

// Monotonic-generation group barrier across the 8 blocks of one batch.
__device__ __forceinline__ void group_barrier(unsigned* cnt, unsigned* gen, unsigned tg) {
    __syncthreads();
    if (threadIdx.x == 0) {
        unsigned prev = __hip_atomic_fetch_add(cnt, 1u, __ATOMIC_ACQ_REL, __HIP_MEMORY_SCOPE_AGENT);
        if (prev == tg * (unsigned)G - 1u) {
            __hip_atomic_store(gen, tg, __ATOMIC_RELEASE, __HIP_MEMORY_SCOPE_AGENT);
        } else {
            unsigned gv;
            do {
                gv = __hip_atomic_load(gen, __ATOMIC_ACQUIRE, __HIP_MEMORY_SCOPE_AGENT);
            } while (gv < tg);
        }
    }
    __syncthreads();
}

// ---------------------------------------------------------------------------
// f32 GEMM + bias: C[M][N] = A @ B + bias. 64x64 tile, 256 thr, 4x4/thread.
// ---------------------------------------------------------------------------
__global__ __launch_bounds__(256) void gemm_bias_kernel(
    const float* __restrict__ A, const float* __restrict__ B,
    const float* __restrict__ bias, float* __restrict__ C,
    int M, int N, int K)
{
    __shared__ float As[16][68];
    __shared__ float Bs[16][68];
    const int tid = threadIdx.x;
    const int bm = blockIdx.x * 64;
    const int bn = blockIdx.y * 64;
    const int tx = tid & 15, ty = tid >> 4;
    const int ar = tid >> 2, ac = (tid & 3) * 4;
    const int br = tid >> 4, bc = (tid & 15) * 4;
    float acc[4][4] = {};

    for (int k0 = 0; k0 < K; k0 += 16) {
        float4 av = *(const float4*)(A + (size_t)(bm + ar) * K + k0 + ac);
        float4 bv = *(const float4*)(B + (size_t)(k0 + br) * N + bn + bc);
        As[ac + 0][ar] = av.x; As[ac + 1][ar] = av.y;
        As[ac + 2][ar] = av.z; As[ac + 3][ar] = av.w;
        *(float4*)(&Bs[br][bc]) = bv;
        __syncthreads();
#pragma unroll
        for (int kk = 0; kk < 16; ++kk) {
            float a0 = As[kk][ty*4+0], a1 = As[kk][ty*4+1];
            float a2 = As[kk][ty*4+2], a3 = As[kk][ty*4+3];
            float b0 = Bs[kk][tx*4+0], b1 = Bs[kk][tx*4+1];
            float b2 = Bs[kk][tx*4+2], b3 = Bs[kk][tx*4+3];
            acc[0][0]+=a0*b0; acc[0][1]+=a0*b1; acc[0][2]+=a0*b2; acc[0][3]+=a0*b3;
            acc[1][0]+=a1*b0; acc[1][1]+=a1*b1; acc[1][2]+=a1*b2; acc[1][3]+=a1*b3;
            acc[2][0]+=a2*b0; acc[2][1]+=a2*b1; acc[2][2]+=a2*b2; acc[2][3]+=a2*b3;
            acc[3][0]+=a3*b0; acc[3][1]+=a3*b1; acc[3][2]+=a3*b2; acc[3][3]+=a3*b3;
        }
        __syncthreads();
    }
#pragma unroll
    for (int i = 0; i < 4; ++i)
#pragma unroll
        for (int j = 0; j < 4; ++j) {
            int cn = bn + tx * 4 + j;
            C[(size_t)(bm + ty * 4 + i) * N + cn] = acc[i][j] + bias[cn];
        }
}

// ---------------------------------------------------------------------------
// Same GEMM but stores transposed per-batch: CT[b][n][m] (m within batch, 512)
// A rows are batch-major (512 rows per batch). M=8192, N=256, K=256.
// ---------------------------------------------------------------------------
__global__ __launch_bounds__(256) void gemm_bias_T_kernel(
    const float* __restrict__ A, const float* __restrict__ B,
    const float* __restrict__ bias, float* __restrict__ CT,
    int M, int N, int K)
{
    __shared__ float As[16][68];
    __shared__ float Bs[16][68];
    __shared__ float Ts[64][65];
    const int tid = threadIdx.x;
    const int bm = blockIdx.x * 64;
    const int bn = blockIdx.y * 64;
    const int tx = tid & 15, ty = tid >> 4;
    const int ar = tid >> 2, ac = (tid & 3) * 4;
    const int br = tid >> 4, bc = (tid & 15) * 4;
    float acc[4][4] = {};

    for (int k0 = 0; k0 < K; k0 += 16) {
        float4 av = *(const float4*)(A + (size_t)(bm + ar) * K + k0 + ac);
        float4 bv = *(const float4*)(B + (size_t)(k0 + br) * N + bn + bc);
        As[ac + 0][ar] = av.x; As[ac + 1][ar] = av.y;
        As[ac + 2][ar] = av.z; As[ac + 3][ar] = av.w;
        *(float4*)(&Bs[br][bc]) = bv;
        __syncthreads();
#pragma unroll
        for (int kk = 0; kk < 16; ++kk) {
            float a0 = As[kk][ty*4+0], a1 = As[kk][ty*4+1];
            float a2 = As[kk][ty*4+2], a3 = As[kk][ty*4+3];
            float b0 = Bs[kk][tx*4+0], b1 = Bs[kk][tx*4+1];
            float b2 = Bs[kk][tx*4+2], b3 = Bs[kk][tx*4+3];
            acc[0][0]+=a0*b0; acc[0][1]+=a0*b1; acc[0][2]+=a0*b2; acc[0][3]+=a0*b3;
            acc[1][0]+=a1*b0; acc[1][1]+=a1*b1; acc[1][2]+=a1*b2; acc[1][3]+=a1*b3;
            acc[2][0]+=a2*b0; acc[2][1]+=a2*b1; acc[2][2]+=a2*b2; acc[2][3]+=a2*b3;
            acc[3][0]+=a3*b0; acc[3][1]+=a3*b1; acc[3][2]+=a3*b2; acc[3][3]+=a3*b3;
        }
        __syncthreads();
    }
#pragma unroll
    for (int i = 0; i < 4; ++i)
#pragma unroll
        for (int j = 0; j < 4; ++j)
            Ts[tx * 4 + j][ty * 4 + i] = acc[i][j] + bias[bn + tx * 4 + j];
    __syncthreads();
    const int jr = tid >> 2, ms = (tid & 3) * 16;
    const int b = bm >> 9, m0 = bm & 511;
    float* dst = CT + (size_t)b * (256 * 512) + (size_t)(bn + jr) * 512 + m0 + ms;
#pragma unroll
    for (int u = 0; u < 16; ++u)
        dst[u] = Ts[jr][ms + u];
}

// ---------------------------------------------------------------------------
// Persistent scan kernel: 128 blocks (8 per batch), 512 threads.
// ---------------------------------------------------------------------------
__global__ __launch_bounds__(NTHR, 1) void rnn_persistent(
    const float* __restrict__ attended,
    const float* __restrict__ query_W, const float* __restrict__ query_b,
    const float* __restrict__ attn_W,
    const float* __restrict__ lstm_W,  const float* __restrict__ lstm_U,
    const float* __restrict__ keysT,   const float* __restrict__ pre,
    float* psbuf, float* ctxbuf, float* hcomm,
    unsigned* barr,
    float* __restrict__ seq, float* __restrict__ hT, float* __restrict__ cT)
{
    const int bid = blockIdx.x;
    const int b = bid >> 3, g = bid & 7;
    const int tid = threadIdx.x;

    __shared__ float U_s[256][128];     // 128 KB: lstm_U col-slice of block g
    __shared__ float xin_s[512];        // [0:256) ctx, [256:512) h
    __shared__ float q_s[32];
    __shared__ float qp_s[16][32];
    __shared__ float a_s[512];
    __shared__ float red_s[8];
    __shared__ float ctxp_s[2][256];
    __shared__ float zp_s[4][128];
    __shared__ float z_s[128];
    __shared__ float c_s[32];
    __shared__ float aw_s[32];

    // ---- prologue: cache U slice (cols: gate*256 + g*32 + uu) ----
    for (int idx = tid; idx < 256 * 128; idx += NTHR) {
        int k = idx >> 7, cc = idx & 127;
        U_s[k][cc] = lstm_U[(size_t)k * ZDIM + ((cc >> 5) << 8) + g * 32 + (cc & 31)];
    }
    if (tid < 32) { aw_s[tid] = attn_W[g * 32 + tid]; c_s[tid] = 0.0f; }
    if (tid < 256) xin_s[256 + tid] = 0.0f;   // h0 = 0
    __syncthreads();

    const float* keysTb = keysT + (size_t)b * 256 * 512;
    const float* attb   = attended + (size_t)b * MSLOTS * DIN;
    const float* preb   = pre + (size_t)b * TSTEPS * ZDIM;
    float* psb  = psbuf + (size_t)(b * G + g) * 512;
    float* ctxb = ctxbuf + (size_t)(b * G + g) * 256;
    float* hcb  = hcomm + (size_t)b * 256;
    unsigned* cnt = barr + b * 32;
    unsigned* gen = barr + 512 + b * 32;

    for (int t = 0; t < TSTEPS; ++t) {
        // ---- phase 1: q slice (32 outputs) from h ----
        {
            int j = tid & 31, kc = tid >> 5;
            const float* Wq = query_W + (size_t)(kc * 16) * UNITS + g * 32 + j;
            float acc = 0.0f;
#pragma unroll
            for (int kk = 0; kk < 16; ++kk)
                acc += xin_s[256 + kc * 16 + kk] * Wq[(size_t)kk * UNITS];
            qp_s[kc][j] = acc;
        }
        __syncthreads();
        if (tid < 32) {
            float acc = query_b[g * 32 + tid];
#pragma unroll
            for (int kc = 0; kc < 16; ++kc) acc += qp_s[kc][tid];
            q_s[tid] = acc;
        }
        __syncthreads();

        // ---- phase 2: partial scores over j-slice, all 512 m ----
        {
            int m = tid;
            float s = 0.0f;
#pragma unroll 4
            for (int j = 0; j < 32; ++j) {
                float kv = keysTb[(size_t)(g * 32 + j) * 512 + m];
                s += aw_s[j] * tanhf_fast(kv + q_s[j]);
            }
            st_agent(&psb[m], s);
        }
        group_barrier(cnt, gen, 3u * t + 1u);

        // ---- phase 3: finalize scores + softmax (redundant per block) ----
        float sc = 0.0f;
        {
            const float* pb = psbuf + (size_t)b * G * 512;
#pragma unroll
            for (int gg = 0; gg < G; ++gg)
                sc += ld_agent(&pb[gg * 512 + tid]);
        }
        float mx = sc;
#pragma unroll
        for (int off = 32; off; off >>= 1) mx = fmaxf(mx, __shfl_xor(mx, off));
        if ((tid & 63) == 0) red_s[tid >> 6] = mx;
        __syncthreads();
        mx = red_s[0];
#pragma unroll
        for (int i = 1; i < 8; ++i) mx = fmaxf(mx, red_s[i]);
        float p = __expf(sc - mx);
        float sm = p;
#pragma unroll
        for (int off = 32; off; off >>= 1) sm += __shfl_xor(sm, off);
        __syncthreads();
        if ((tid & 63) == 0) red_s[tid >> 6] = sm;
        __syncthreads();
        float tot = red_s[0];
#pragma unroll
        for (int i = 1; i < 8; ++i) tot += red_s[i];
        a_s[tid] = p / tot;
        __syncthreads();

        // ---- phase 4: partial ctx over m-slice (64 m) ----
        {
            int k = tid & 255, mh = tid >> 8;
            const float* ab = attb + (size_t)(g * 64 + mh * 32) * DIN + k;
            float acc = 0.0f;
#pragma unroll 4
            for (int mm = 0; mm < 32; ++mm)
                acc += a_s[g * 64 + mh * 32 + mm] * ab[(size_t)mm * DIN];
            ctxp_s[mh][k] = acc;
        }
        __syncthreads();
        if (tid < 256)
            st_agent(&ctxb[tid], ctxp_s[0][tid] + ctxp_s[1][tid]);
        group_barrier(cnt, gen, 3u * t + 2u);

        // ---- phase 5: gather full ctx ----
        if (tid < 256) {
            const float* cb = ctxbuf + (size_t)b * G * 256;
            float v = 0.0f;
#pragma unroll
            for (int gg = 0; gg < G; ++gg)
                v += ld_agent(&cb[gg * 256 + tid]);
            xin_s[tid] = v;
        }
        __syncthreads();

        // ---- phase 6: z slice (128 cols) ----
        {
            int cc = tid & 127, kh = tid >> 7;   // wave-uniform kh
            float acc = 0.0f;
            if (kh < 2) {
                const float* w = lstm_W + (size_t)(256 + kh * 128) * ZDIM
                               + ((cc >> 5) << 8) + g * 32 + (cc & 31);
#pragma unroll 4
                for (int kk = 0; kk < 128; ++kk)
                    acc += xin_s[kh * 128 + kk] * w[(size_t)kk * ZDIM];
            } else {
                int k0 = (kh - 2) * 128;
#pragma unroll 8
                for (int kk = 0; kk < 128; ++kk)
                    acc += xin_s[256 + k0 + kk] * U_s[k0 + kk][cc];
            }
            zp_s[kh][cc] = acc;
        }
        __syncthreads();
        if (tid < 128) {
            float z = preb[(size_t)t * ZDIM + ((tid >> 5) << 8) + g * 32 + (tid & 31)]
                    + zp_s[0][tid] + zp_s[1][tid] + zp_s[2][tid] + zp_s[3][tid];
            z_s[tid] = z;
        }
        __syncthreads();

        // ---- phase 7: gates, state update, outputs ----
        if (tid < 32) {
            float zi = z_s[tid], zf = z_s[32 + tid], zg = z_s[64 + tid], zo = z_s[96 + tid];
            float ig = sigmoidf_fast(zi);
            float fg = sigmoidf_fast(zf);
            float gg = tanhf_fast(zg);
            float og = sigmoidf_fast(zo);
            float cn = fg * c_s[tid] + ig * gg;
            float hn = og * tanhf_fast(cn);
            c_s[tid] = cn;
            int u = g * 32 + tid;
            st_agent(&hcb[u], hn);
            seq[((size_t)b * TSTEPS + t) * UNITS + u] = hn;
            if (t == TSTEPS - 1) { hT[b * UNITS + u] = hn; cT[b * UNITS + u] = cn; }
        }
        group_barrier(cnt, gen, 3u * t + 3u);

        // ---- phase 8: gather full h ----
        if (tid < 256)
            xin_s[256 + tid] = ld_agent(&hcb[tid]);
        __syncthreads();
    }
}

// ---------------------------------------------------------------------------
extern "C" void kernel_launch(void* const* d_in, const int* in_sizes, int n_in,
                              void* d_out, int out_size, void* d_ws, size_t ws_size,
                              hipStream_t stream)
{
    (void)in_sizes; (void)n_in; (void)out_size; (void)ws_size;
    const float* inputs   = (const float*)d_in[0];
    const float* attended = (const float*)d_in[1];
    const float* key_W    = (const float*)d_in[2];
    const float* key_b    = (const float*)d_in[3];
    const float* query_W  = (const float*)d_in[4];
    const float* query_b  = (const float*)d_in[5];
    const float* attn_W   = (const float*)d_in[6];
    const float* lstm_W   = (const float*)d_in[8];
    const float* lstm_U   = (const float*)d_in[9];
    const float* lstm_b   = (const float*)d_in[10];
    // attn_b (d_in[7]) cancels in softmax — dropped.

    float* out = (float*)d_out;
    float* seq = out;
    float* hT  = out + (size_t)BATCH * TSTEPS * UNITS;
    float* cT  = hT + BATCH * UNITS;

    float* ws = (float*)d_ws;
    float* keysT  = ws;                         // 16*256*512 = 2,097,152
    float* pre    = keysT + 2097152;            // 16*128*1024 = 2,097,152
    float* psbuf  = pre + 2097152;              // 16*8*512 = 65,536
    float* ctxbuf = psbuf + 65536;              // 16*8*256 = 32,768
    float* hcomm  = ctxbuf + 32768;             // 16*256 = 4,096
    unsigned* barr = (unsigned*)(hcomm + 4096); // 1024 u32 (cnt + gen, padded)

    hipMemsetAsync(barr, 0, 4096, stream);

    // keysT[b][j][m] = (attended @ key_W + key_b)^T per batch
    gemm_bias_T_kernel<<<dim3(128, 4), 256, 0, stream>>>(
        attended, key_W, key_b, keysT, 8192, 256, 256);
    // pre = inputs @ lstm_W[:256] + lstm_b
    gemm_bias_kernel<<<dim3(32, 16), 256, 0, stream>>>(
        inputs, lstm_W, lstm_b, pre, 2048, 1024, 256);

    rnn_persistent<<<dim3(NBLK), dim3(NTHR), 0, stream>>>(
        attended, query_W, query_b, attn_W, lstm_W, lstm_U,
        keysT, pre, psbuf, ctxbuf, hcomm, barr, seq, hT, cT);
}

// Round 3
// 3452.463 us; speedup vs baseline: 1.4902x; 1.2647x over previous
//
#include <hip/hip_runtime.h>
#include <hip/hip_bf16.h>
#include <cstddef>

#define BATCH 16
#define TSTEPS 128
#define MSLOTS 512
#define DIN 256
#define UNITS 256
#define ZDIM 1024
#define G 8          // blocks per batch
#define NBLK (BATCH*G)
#define NTHR 512

__device__ __forceinline__ float tanhf_fast(float x) {
    float e = __expf(2.0f * x);
    return 1.0f - 2.0f / (e + 1.0f);
}
__device__ __forceinline__ float sigmoidf_fast(float x) {
    return 1.0f / (1.0f + __expf(-x));
}
__device__ __forceinline__ void st_agent(float* p, float v) {
    __hip_atomic_store(p, v, __ATOMIC_RELAXED, __HIP_MEMORY_SCOPE_AGENT);
}
__device__ __forceinline__ float ld_agent(const float* p) {
    return __hip_atomic_load(p, __ATOMIC_RELAXED, __HIP_MEMORY_SCOPE_AGENT);
}

// Flag-line barrier across the 8 blocks of one batch. fl = 16-word line for
// this batch (only words 0..7 used). Monotonic generation tg, no RMW.
__device__ __forceinline__ void barrier_sync(unsigned* fl, int g, unsigned tg) {
    __syncthreads();   // compiler drains vmcnt/lgkmcnt before s_barrier
    if (threadIdx.x == 0)
        __hip_atomic_store(&fl[g], tg, __ATOMIC_RELEASE, __HIP_MEMORY_SCOPE_AGENT);
    if (threadIdx.x < G) {
        while (__hip_atomic_load(&fl[threadIdx.x], __ATOMIC_RELAXED,
                                 __HIP_MEMORY_SCOPE_AGENT) < tg) {}
    }
    __syncthreads();
    __builtin_amdgcn_fence(__ATOMIC_ACQUIRE, "agent");
}

// ---------------------------------------------------------------------------
// f32 GEMM + bias: C[M][N] = A @ B + bias. 64x64 tile, 256 thr, 4x4/thread.
// ---------------------------------------------------------------------------
__global__ __launch_bounds__(256) void gemm_bias_kernel(
    const float* __restrict__ A, const float* __restrict__ B,
    const float* __restrict__ bias, float* __restrict__ C,
    int M, int N, int K)
{
    __shared__ float As[16][68];
    __shared__ float Bs[16][68];
    const int tid = threadIdx.x;
    const int bm = blockIdx.x * 64;
    const int bn = blockIdx.y * 64;
    const int tx = tid & 15, ty = tid >> 4;
    const int ar = tid >> 2, ac = (tid & 3) * 4;
    const int br = tid >> 4, bc = (tid & 15) * 4;
    float acc[4][4] = {};

    for (int k0 = 0; k0 < K; k0 += 16) {
        float4 av = *(const float4*)(A + (size_t)(bm + ar) * K + k0 + ac);
        float4 bv = *(const float4*)(B + (size_t)(k0 + br) * N + bn + bc);
        As[ac + 0][ar] = av.x; As[ac + 1][ar] = av.y;
        As[ac + 2][ar] = av.z; As[ac + 3][ar] = av.w;
        *(float4*)(&Bs[br][bc]) = bv;
        __syncthreads();
#pragma unroll
        for (int kk = 0; kk < 16; ++kk) {
            float a0 = As[kk][ty*4+0], a1 = As[kk][ty*4+1];
            float a2 = As[kk][ty*4+2], a3 = As[kk][ty*4+3];
            float b0 = Bs[kk][tx*4+0], b1 = Bs[kk][tx*4+1];
            float b2 = Bs[kk][tx*4+2], b3 = Bs[kk][tx*4+3];
            acc[0][0]+=a0*b0; acc[0][1]+=a0*b1; acc[0][2]+=a0*b2; acc[0][3]+=a0*b3;
            acc[1][0]+=a1*b0; acc[1][1]+=a1*b1; acc[1][2]+=a1*b2; acc[1][3]+=a1*b3;
            acc[2][0]+=a2*b0; acc[2][1]+=a2*b1; acc[2][2]+=a2*b2; acc[2][3]+=a2*b3;
            acc[3][0]+=a3*b0; acc[3][1]+=a3*b1; acc[3][2]+=a3*b2; acc[3][3]+=a3*b3;
        }
        __syncthreads();
    }
#pragma unroll
    for (int i = 0; i < 4; ++i)
#pragma unroll
        for (int j = 0; j < 4; ++j) {
            int cn = bn + tx * 4 + j;
            C[(size_t)(bm + ty * 4 + i) * N + cn] = acc[i][j] + bias[cn];
        }
}

// ---------------------------------------------------------------------------
// GEMM storing transposed per-batch: CT[b][n][m], A rows batch-major (512/batch)
// ---------------------------------------------------------------------------
__global__ __launch_bounds__(256) void gemm_bias_T_kernel(
    const float* __restrict__ A, const float* __restrict__ B,
    const float* __restrict__ bias, float* __restrict__ CT,
    int M, int N, int K)
{
    __shared__ float As[16][68];
    __shared__ float Bs[16][68];
    __shared__ float Ts[64][65];
    const int tid = threadIdx.x;
    const int bm = blockIdx.x * 64;
    const int bn = blockIdx.y * 64;
    const int tx = tid & 15, ty = tid >> 4;
    const int ar = tid >> 2, ac = (tid & 3) * 4;
    const int br = tid >> 4, bc = (tid & 15) * 4;
    float acc[4][4] = {};

    for (int k0 = 0; k0 < K; k0 += 16) {
        float4 av = *(const float4*)(A + (size_t)(bm + ar) * K + k0 + ac);
        float4 bv = *(const float4*)(B + (size_t)(k0 + br) * N + bn + bc);
        As[ac + 0][ar] = av.x; As[ac + 1][ar] = av.y;
        As[ac + 2][ar] = av.z; As[ac + 3][ar] = av.w;
        *(float4*)(&Bs[br][bc]) = bv;
        __syncthreads();
#pragma unroll
        for (int kk = 0; kk < 16; ++kk) {
            float a0 = As[kk][ty*4+0], a1 = As[kk][ty*4+1];
            float a2 = As[kk][ty*4+2], a3 = As[kk][ty*4+3];
            float b0 = Bs[kk][tx*4+0], b1 = Bs[kk][tx*4+1];
            float b2 = Bs[kk][tx*4+2], b3 = Bs[kk][tx*4+3];
            acc[0][0]+=a0*b0; acc[0][1]+=a0*b1; acc[0][2]+=a0*b2; acc[0][3]+=a0*b3;
            acc[1][0]+=a1*b0; acc[1][1]+=a1*b1; acc[1][2]+=a1*b2; acc[1][3]+=a1*b3;
            acc[2][0]+=a2*b0; acc[2][1]+=a2*b1; acc[2][2]+=a2*b2; acc[2][3]+=a2*b3;
            acc[3][0]+=a3*b0; acc[3][1]+=a3*b1; acc[3][2]+=a3*b2; acc[3][3]+=a3*b3;
        }
        __syncthreads();
    }
#pragma unroll
    for (int i = 0; i < 4; ++i)
#pragma unroll
        for (int j = 0; j < 4; ++j)
            Ts[tx * 4 + j][ty * 4 + i] = acc[i][j] + bias[bn + tx * 4 + j];
    __syncthreads();
    const int jr = tid >> 2, ms = (tid & 3) * 16;
    const int b = bm >> 9, m0 = bm & 511;
    float* dst = CT + (size_t)b * (256 * 512) + (size_t)(bn + jr) * 512 + m0 + ms;
#pragma unroll
    for (int u = 0; u < 16; ++u)
        dst[u] = Ts[jr][ms + u];
}

// ---------------------------------------------------------------------------
// Persistent scan kernel: 128 blocks (8 per batch, XCD-clustered), 512 thr.
// All t-invariant operands live in LDS (keysT, attended slices) or registers
// (lstm_W2/lstm_U/query_W slices). Recurrent loop touches global only for
// comm buffers, pre (512B/step) and outputs.
// ---------------------------------------------------------------------------
__global__ __launch_bounds__(NTHR, 2) void rnn_persistent(
    const float* __restrict__ attended,
    const float* __restrict__ query_W, const float* __restrict__ query_b,
    const float* __restrict__ attn_W,
    const float* __restrict__ lstm_W,  const float* __restrict__ lstm_U,
    const float* __restrict__ keysT,   const float* __restrict__ pre,
    float* psbuf, float* ctxbuf, float* hcomm,
    unsigned* flags,
    float* __restrict__ seq, float* __restrict__ hT, float* __restrict__ cT)
{
    const int bid = blockIdx.x;
    // XCD clustering: presumed XCD = bid % 8; batch b occupies bids == (b>>1) mod 8
    const int x = bid & 7;
    const int s = bid >> 3;          // 0..15
    const int b = x * 2 + (s >> 3);
    const int g = s & 7;
    const int tid = threadIdx.x;

    __shared__ float keysT_s[32][512];   // 64 KB, t-invariant
    __shared__ float att_s[64][256];     // 64 KB, t-invariant
    __shared__ float xin_s[512];         // [0:256) ctx, [256:512) h
    __shared__ float q_s[32];
    __shared__ float qp_s[16][32];
    __shared__ float a_s[512];
    __shared__ float red_s[8];
    __shared__ float ctxp_s[2][256];
    __shared__ float zp_s[4][128];
    __shared__ float z_s[128];
    __shared__ float c_s[32];
    __shared__ float aw_s[32];

    const float* keysTb = keysT + (size_t)b * 256 * 512;
    const float* attb   = attended + (size_t)b * MSLOTS * DIN;
    const float* preb   = pre + (size_t)b * TSTEPS * ZDIM;
    float* psb  = psbuf + (size_t)(b * G + g) * 512;
    float* ctxb = ctxbuf + (size_t)(b * G + g) * 256;
    float* hcb  = hcomm + (size_t)b * 256;
    unsigned* fl = flags + b * 16;       // one 64B line per batch

    // ---- stage keysT slice (j = g*32..g*32+31, all 512 m) ----
    for (int idx = tid * 4; idx < 32 * 512; idx += NTHR * 4) {
        int j = idx >> 9, m = idx & 511;
        *(float4*)&keysT_s[j][m] = *(const float4*)&keysTb[(size_t)(g * 32 + j) * 512 + m];
    }
    // ---- stage attended slice (m = g*64..g*64+63, all 256 k) ----
    for (int idx = tid * 4; idx < 64 * 256; idx += NTHR * 4) {
        int mm = idx >> 8, k = idx & 255;
        *(float4*)&att_s[mm][k] = *(const float4*)&attb[(size_t)(g * 64 + mm) * 256 + k];
    }

    // ---- weights into registers (held across all 128 steps) ----
    // phase-6 role: cc = tid&127 (col within slice), kh = tid>>7 (k-quarter)
    const int cc = tid & 127, kh = tid >> 7;
    const int col = ((cc >> 5) << 8) + g * 32 + (cc & 31);   // gate*256 + g*32 + u
    const float* gw = (kh < 2)
        ? (lstm_W + (size_t)(256 + kh * 128) * ZDIM + col)
        : (lstm_U + (size_t)((kh - 2) * 128) * ZDIM + col);
    float w[128];
#pragma unroll
    for (int kk = 0; kk < 128; ++kk) w[kk] = gw[(size_t)kk * ZDIM];

    // phase-1 role: jq = tid&31 (q col within slice), kc = tid>>5 (k-chunk of 16)
    const int jq = tid & 31, kc = tid >> 5;
    float wq[16];
#pragma unroll
    for (int kk = 0; kk < 16; ++kk)
        wq[kk] = query_W[(size_t)(kc * 16 + kk) * UNITS + g * 32 + jq];

    float qb_r = (tid < 32) ? query_b[g * 32 + tid] : 0.0f;
    if (tid < 32) { aw_s[tid] = attn_W[g * 32 + tid]; c_s[tid] = 0.0f; }
    if (tid < 256) xin_s[256 + tid] = 0.0f;   // h0 = 0
    __syncthreads();

    for (int t = 0; t < TSTEPS; ++t) {
        // hoisted pre load (hidden under phases 1-5)
        float pre_r = 0.0f;
        if (tid < 128)
            pre_r = preb[(size_t)t * ZDIM + ((tid >> 5) << 8) + g * 32 + (tid & 31)];

        // ---- phase 1: q slice (32 outputs) from h ----
        {
            float acc = 0.0f;
#pragma unroll
            for (int kk = 0; kk < 16; ++kk)
                acc += xin_s[256 + kc * 16 + kk] * wq[kk];
            qp_s[kc][jq] = acc;
        }
        __syncthreads();
        if (tid < 32) {
            float acc = qb_r;
#pragma unroll
            for (int k2 = 0; k2 < 16; ++k2) acc += qp_s[k2][tid];
            q_s[tid] = acc;
        }
        __syncthreads();

        // ---- phase 2: partial scores over j-slice, all 512 m (LDS only) ----
        {
            float sacc = 0.0f;
#pragma unroll 8
            for (int j = 0; j < 32; ++j)
                sacc += aw_s[j] * tanhf_fast(keysT_s[j][tid] + q_s[j]);
            st_agent(&psb[tid], sacc);
        }
        barrier_sync(fl, g, 3u * t + 1u);

        // ---- phase 3: finalize scores + softmax (redundant per block) ----
        float sc = 0.0f;
        {
            const float* pb = psbuf + (size_t)b * G * 512;
#pragma unroll
            for (int gg = 0; gg < G; ++gg)
                sc += ld_agent(&pb[gg * 512 + tid]);
        }
        float mx = sc;
#pragma unroll
        for (int off = 32; off; off >>= 1) mx = fmaxf(mx, __shfl_xor(mx, off));
        if ((tid & 63) == 0) red_s[tid >> 6] = mx;
        __syncthreads();
        mx = red_s[0];
#pragma unroll
        for (int i = 1; i < 8; ++i) mx = fmaxf(mx, red_s[i]);
        float p = __expf(sc - mx);
        float sm = p;
#pragma unroll
        for (int off = 32; off; off >>= 1) sm += __shfl_xor(sm, off);
        __syncthreads();
        if ((tid & 63) == 0) red_s[tid >> 6] = sm;
        __syncthreads();
        float tot = red_s[0];
#pragma unroll
        for (int i = 1; i < 8; ++i) tot += red_s[i];
        a_s[tid] = p * (1.0f / tot);
        __syncthreads();

        // ---- phase 4: partial ctx over m-slice (64 m, LDS only) ----
        {
            int k = tid & 255, mh = tid >> 8;
            float acc = 0.0f;
#pragma unroll 8
            for (int mm = 0; mm < 32; ++mm)
                acc += a_s[g * 64 + mh * 32 + mm] * att_s[mh * 32 + mm][k];
            ctxp_s[mh][k] = acc;
        }
        __syncthreads();
        if (tid < 256)
            st_agent(&ctxb[tid], ctxp_s[0][tid] + ctxp_s[1][tid]);
        barrier_sync(fl, g, 3u * t + 2u);

        // ---- phase 5: gather full ctx ----
        if (tid < 256) {
            const float* cb = ctxbuf + (size_t)b * G * 256;
            float v = 0.0f;
#pragma unroll
            for (int gg = 0; gg < G; ++gg)
                v += ld_agent(&cb[gg * 256 + tid]);
            xin_s[tid] = v;
        }
        __syncthreads();

        // ---- phase 6: z slice (128 cols) — weights from registers ----
        {
            float acc = 0.0f;
#pragma unroll
            for (int kk = 0; kk < 128; ++kk)
                acc += xin_s[kh * 128 + kk] * w[kk];
            zp_s[kh][cc] = acc;
        }
        __syncthreads();
        if (tid < 128)
            z_s[tid] = pre_r + zp_s[0][tid] + zp_s[1][tid] + zp_s[2][tid] + zp_s[3][tid];
        __syncthreads();

        // ---- phase 7: gates, state update, outputs ----
        if (tid < 32) {
            float zi = z_s[tid], zf = z_s[32 + tid], zg = z_s[64 + tid], zo = z_s[96 + tid];
            float ig = sigmoidf_fast(zi);
            float fg = sigmoidf_fast(zf);
            float gg = tanhf_fast(zg);
            float og = sigmoidf_fast(zo);
            float cn = fg * c_s[tid] + ig * gg;
            float hn = og * tanhf_fast(cn);
            c_s[tid] = cn;
            int u = g * 32 + tid;
            st_agent(&hcb[u], hn);
            seq[((size_t)b * TSTEPS + t) * UNITS + u] = hn;
            if (t == TSTEPS - 1) { hT[b * UNITS + u] = hn; cT[b * UNITS + u] = cn; }
        }
        barrier_sync(fl, g, 3u * t + 3u);

        // ---- phase 8: gather full h ----
        if (tid < 256)
            xin_s[256 + tid] = ld_agent(&hcb[tid]);
        __syncthreads();
    }
}

// ---------------------------------------------------------------------------
extern "C" void kernel_launch(void* const* d_in, const int* in_sizes, int n_in,
                              void* d_out, int out_size, void* d_ws, size_t ws_size,
                              hipStream_t stream)
{
    (void)in_sizes; (void)n_in; (void)out_size; (void)ws_size;
    const float* inputs   = (const float*)d_in[0];
    const float* attended = (const float*)d_in[1];
    const float* key_W    = (const float*)d_in[2];
    const float* key_b    = (const float*)d_in[3];
    const float* query_W  = (const float*)d_in[4];
    const float* query_b  = (const float*)d_in[5];
    const float* attn_W   = (const float*)d_in[6];
    const float* lstm_W   = (const float*)d_in[8];
    const float* lstm_U   = (const float*)d_in[9];
    const float* lstm_b   = (const float*)d_in[10];
    // attn_b (d_in[7]) cancels in softmax — dropped.

    float* out = (float*)d_out;
    float* seq = out;
    float* hT  = out + (size_t)BATCH * TSTEPS * UNITS;
    float* cT  = hT + BATCH * UNITS;

    float* ws = (float*)d_ws;
    float* keysT  = ws;                         // 16*256*512 = 2,097,152
    float* pre    = keysT + 2097152;            // 16*128*1024 = 2,097,152
    float* psbuf  = pre + 2097152;              // 16*8*512 = 65,536
    float* ctxbuf = psbuf + 65536;              // 16*8*256 = 32,768
    float* hcomm  = ctxbuf + 32768;             // 16*256 = 4,096
    unsigned* flags = (unsigned*)(hcomm + 4096); // 16*16 u32 = 1 KB

    hipMemsetAsync(flags, 0, BATCH * 16 * sizeof(unsigned), stream);

    // keysT[b][j][m] = (attended @ key_W + key_b)^T per batch
    gemm_bias_T_kernel<<<dim3(128, 4), 256, 0, stream>>>(
        attended, key_W, key_b, keysT, 8192, 256, 256);
    // pre = inputs @ lstm_W[:256] + lstm_b
    gemm_bias_kernel<<<dim3(32, 16), 256, 0, stream>>>(
        inputs, lstm_W, lstm_b, pre, 2048, 1024, 256);

    rnn_persistent<<<dim3(NBLK), dim3(NTHR), 0, stream>>>(
        attended, query_W, query_b, attn_W, lstm_W, lstm_U,
        keysT, pre, psbuf, ctxbuf, hcomm, flags, seq, hT, cT);
}